// Round 2
// baseline (63.939 us; speedup 1.0000x reference)
//
#include <hip/hip_runtime.h>
#include <math.h>

#define N_PART 50000
#define KMAX 80
#define KS 4

// ---------------------------------------------------------------------------
// Mask-dtype detection: numpy bool may arrive as 1-byte bools or as int32.
// If any aligned int32 word is outside {0,1}, storage must be byte-bools
// (runs of consecutive True pack into 0x01010101). One wave, 512 words.
// ---------------------------------------------------------------------------
__global__ void detect_mask_kernel(const int* __restrict__ m, int* __restrict__ flag) {
    int lane = threadIdx.x;
    bool big = false;
    for (int i = lane; i < 512; i += 64) {
        int v = m[i];
        if (v > 1 || v < 0) big = true;
    }
    unsigned long long b = __ballot(big);
    if (lane == 0) flag[0] = (b != 0ULL) ? 1 : 0;   // 1 => byte-bool storage
}

template <typename MT>
__device__ __forceinline__ void accumulate_particle(
    int p, int sub,
    const float* __restrict__ pos,
    const float* __restrict__ vel,
    const MT* __restrict__ nmask,
    const int* __restrict__ nidx,
    const float* __restrict__ Ws,
    float& acc0, float& acc1, float& acc2)
{
    const float inv_r = 1.0f / 0.3f;
    const float eps   = 1e-12f;
    const float FOUR_OVER_PI = 1.27323954473516268615f;

    float cpx = pos[p * 3 + 0];
    float cpy = pos[p * 3 + 1];
    float cpz = pos[p * 3 + 2];

    const int base = p * KMAX;
    for (int j = 0; j < KMAX / 4; ++j) {
        int k = sub + 4 * j;
        if (!nmask[base + k]) break;   // mask is a prefix per row
        int idx = nidx[base + k];

        float rx = (pos[idx * 3 + 0] - cpx) * inv_r;
        float ry = (pos[idx * 3 + 1] - cpy) * inv_r;
        float rz = (pos[idx * 3 + 2] - cpz) * inv_r;

        float sq = rx * rx + ry * ry + rz * rz;

        // window_poly6 on normalized squared distance
        float t1  = 1.0f - sq;
        float imp = fminf(fmaxf(t1 * t1 * t1, 0.0f), 1.0f);

        // ---- ball -> cylinder (volume preserving) ----
        float norm  = sqrtf(fmaxf(sq, eps));
        float sq_xy = rx * rx + ry * ry;
        float x1, y1, z1;
        if (1.25f * rz * rz > sq_xy) {
            float s_top = sqrtf(3.0f * norm / (norm + fabsf(rz)));
            x1 = rx * s_top;
            y1 = ry * s_top;
            z1 = copysignf(norm, rz);
        } else {
            float s_side = norm / sqrtf(fmaxf(sq_xy, eps));
            x1 = rx * s_side;
            y1 = ry * s_side;
            z1 = 1.5f * rz;
        }
        if (sq < eps) { x1 = rx; y1 = ry; z1 = rz; }

        // ---- cylinder -> cube (equal-area disc -> square) ----
        float sq_xy1  = x1 * x1 + y1 * y1;
        float norm_xy = sqrtf(fmaxf(sq_xy1, eps));
        float x2, y2;
        if (fabsf(y1) <= fabsf(x1)) {
            float sx     = copysignf(norm_xy, x1);
            float safe_x = (fabsf(x1) > eps) ? x1 : 1.0f;
            x2 = sx;
            y2 = sx * FOUR_OVER_PI * atanf(y1 / safe_x);
        } else {
            float sy     = copysignf(norm_xy, y1);
            float safe_y = (fabsf(y1) > eps) ? y1 : 1.0f;
            x2 = sy * FOUR_OVER_PI * atanf(x1 / safe_y);
            y2 = sy;
        }
        if (sq_xy1 < eps) { x2 = x1; y2 = y1; }

        // ---- trilinear grid coords, align_corners=True, clamped ----
        float tx = fminf(fmaxf((x2 + 1.0f) * 1.5f, 0.0f), 3.0f);
        float ty = fminf(fmaxf((y2 + 1.0f) * 1.5f, 0.0f), 3.0f);
        float tz = fminf(fmaxf((z1 + 1.0f) * 1.5f, 0.0f), 3.0f);
        float fx0 = floorf(tx), fy0 = floorf(ty), fz0 = floorf(tz);
        int xi0 = (int)fx0, yi0 = (int)fy0, zi0 = (int)fz0;
        int xi1 = min(xi0 + 1, KS - 1);
        int yi1 = min(yi0 + 1, KS - 1);
        int zi1 = min(zi0 + 1, KS - 1);
        float wx1 = tx - fx0, wx0 = 1.0f - wx1;
        float wy1 = ty - fy0, wy0 = 1.0f - wy1;
        float wz1 = tz - fz0, wz0 = 1.0f - wz1;

        float vx = vel[idx * 3 + 0] * imp;
        float vy = vel[idx * 3 + 1] * imp;
        float vz = vel[idx * 3 + 2] * imp;

        int   zi[2] = { zi0, zi1 };  float wz[2] = { wz0, wz1 };
        int   yi[2] = { yi0, yi1 };  float wy[2] = { wy0, wy1 };
        int   xi[2] = { xi0, xi1 };  float wx[2] = { wx0, wx1 };

        #pragma unroll
        for (int cz = 0; cz < 2; ++cz) {
            #pragma unroll
            for (int cy = 0; cy < 2; ++cy) {
                #pragma unroll
                for (int cx = 0; cx < 2; ++cx) {
                    int corner = (zi[cz] * KS + yi[cy]) * KS + xi[cx];
                    float w = wz[cz] * wy[cy] * wx[cx];
                    const float* Wc = &Ws[corner * 12];
                    float q0 = w * vx, q1 = w * vy, q2 = w * vz;
                    acc0 += q0 * Wc[0] + q1 * Wc[3] + q2 * Wc[6];
                    acc1 += q0 * Wc[1] + q1 * Wc[4] + q2 * Wc[7];
                    acc2 += q0 * Wc[2] + q1 * Wc[5] + q2 * Wc[8];
                }
            }
        }
    }
}

__global__ __launch_bounds__(256) void cconv_kernel(
    const float* __restrict__ pos,
    const float* __restrict__ vel,
    const float* __restrict__ Wg,      // [64*3*3] flattened (g, cin, cout)
    const int* __restrict__ nidx,      // [N][KMAX]
    const void* __restrict__ nmask,    // [N][KMAX], dtype per flag
    const int* __restrict__ maskFlag,  // 1 => byte-bool, 0 => int32
    float* __restrict__ out)           // [N][3]
{
    __shared__ float Ws[64 * 12];
    for (int t = threadIdx.x; t < 64 * 12; t += blockDim.x) {
        int g = t / 12, r = t % 12;
        Ws[t] = (r < 9) ? Wg[g * 9 + r] : 0.0f;
    }
    __syncthreads();

    int gid = blockIdx.x * blockDim.x + threadIdx.x;
    int p   = gid >> 2;   // 4 lanes per particle
    int sub = gid & 3;
    if (p >= N_PART) return;

    float acc0 = 0.0f, acc1 = 0.0f, acc2 = 0.0f;

    if (maskFlag[0] != 0) {
        accumulate_particle<unsigned char>(p, sub, pos, vel,
            (const unsigned char*)nmask, nidx, Ws, acc0, acc1, acc2);
    } else {
        accumulate_particle<int>(p, sub, pos, vel,
            (const int*)nmask, nidx, Ws, acc0, acc1, acc2);
    }

    // reduce across the 4 lanes of this particle
    acc0 += __shfl_xor(acc0, 1); acc0 += __shfl_xor(acc0, 2);
    acc1 += __shfl_xor(acc1, 1); acc1 += __shfl_xor(acc1, 2);
    acc2 += __shfl_xor(acc2, 1); acc2 += __shfl_xor(acc2, 2);

    if (sub == 0) {
        out[p * 3 + 0] = acc0;
        out[p * 3 + 1] = acc1;
        out[p * 3 + 2] = acc2;
    }
}

extern "C" void kernel_launch(void* const* d_in, const int* in_sizes, int n_in,
                              void* d_out, int out_size, void* d_ws, size_t ws_size,
                              hipStream_t stream) {
    const float* pos   = (const float*)d_in[0];
    const float* vel   = (const float*)d_in[1];
    const float* Wg    = (const float*)d_in[2];
    const int*   nidx  = (const int*)d_in[3];
    const void*  nmask = d_in[4];
    float*       out   = (float*)d_out;
    int*         flag  = (int*)d_ws;

    detect_mask_kernel<<<1, 64, 0, stream>>>((const int*)nmask, flag);

    int threads = 256;
    int total   = N_PART * 4;
    int grid    = (total + threads - 1) / threads;
    cconv_kernel<<<grid, threads, 0, stream>>>(pos, vel, Wg, nidx, nmask, flag, out);
}

// Round 3
// 50.256 us; speedup vs baseline: 1.2723x; 1.2723x over previous
//
#include <hip/hip_runtime.h>
#include <math.h>

#define N_PART 50000
#define KMAX 80
#define KS 4
#define LPP 16   // lanes per particle

// ---------------------------------------------------------------------------
// Mask-dtype detection: numpy bool may arrive as 1-byte bools or as int32.
// If any aligned int32 word is outside {0,1}, storage must be byte-bools
// (runs of consecutive True pack into 0x01010101). One wave, 512 words.
// ---------------------------------------------------------------------------
__global__ void detect_mask_kernel(const int* __restrict__ m, int* __restrict__ flag) {
    int lane = threadIdx.x;
    bool big = false;
    for (int i = lane; i < 512; i += 64) {
        int v = m[i];
        if (v > 1 || v < 0) big = true;
    }
    unsigned long long b = __ballot(big);
    if (lane == 0) flag[0] = (b != 0ULL) ? 1 : 0;   // 1 => byte-bool storage
}

// Pack [pos.xyz | vel.xyz | 0 | 0] as 32B per particle for 2x dwordx4 gathers.
__global__ __launch_bounds__(256) void pack_pv_kernel(
    const float* __restrict__ pos, const float* __restrict__ vel,
    float4* __restrict__ pv4)
{
    int p = blockIdx.x * blockDim.x + threadIdx.x;
    if (p >= N_PART) return;
    float4 a = make_float4(pos[3*p], pos[3*p+1], pos[3*p+2], vel[3*p]);
    float4 b = make_float4(vel[3*p+1], vel[3*p+2], 0.0f, 0.0f);
    pv4[2*p]     = a;
    pv4[2*p + 1] = b;
}

// Count the true-prefix length of row p using this particle's 16 lanes.
// Lane `sub` scans entries [sub*5, sub*5+5); combine via ballot + shfl.
template <typename MT>
__device__ __forceinline__ int prefix_count(const MT* __restrict__ nmask, int base, int sub) {
    int lc = 0; bool more = true;
    #pragma unroll
    for (int i = 0; i < 5; ++i) {
        bool t = nmask[base + sub * 5 + i] != 0;
        lc += (more && t) ? 1 : 0;
        more = more && t;
    }
    bool full = (lc == 5);
    unsigned long long nb = __ballot(!full);
    int wl  = threadIdx.x & 63;
    int grp = wl >> 4;                       // which 16-lane group in the wave
    unsigned int gb = (unsigned int)((nb >> (16 * grp)) & 0xFFFFull);
    if (gb == 0) return KMAX;
    int fi  = __ffs(gb) - 1;                 // first non-full lane in group
    int flc = __shfl(lc, (grp << 4) + fi, 64);
    return fi * 5 + flc;
}

template <bool PACKED>
__global__ __launch_bounds__(256) void cconv_kernel(
    const float* __restrict__ pos,
    const float* __restrict__ vel,
    const float4* __restrict__ pv4,    // packed [pos|vel], valid if PACKED
    const float* __restrict__ Wg,      // [64*3*3] (g, cin, cout)
    const int* __restrict__ nidx,      // [N][KMAX]
    const void* __restrict__ nmask,    // [N][KMAX], dtype per flag
    const int* __restrict__ maskFlag,  // 1 => byte-bool, 0 => int32
    float* __restrict__ out)           // [N][3]
{
    __shared__ float Ws[64 * 12];
    for (int t = threadIdx.x; t < 64 * 12; t += blockDim.x) {
        int g = t / 12, r = t % 12;
        Ws[t] = (r < 9) ? Wg[g * 9 + r] : 0.0f;
    }
    __syncthreads();

    int gid = blockIdx.x * blockDim.x + threadIdx.x;
    int p   = gid / LPP;
    int sub = gid & (LPP - 1);
    if (p >= N_PART) return;

    const int base = p * KMAX;

    int cnt;
    if (maskFlag[0] != 0) cnt = prefix_count<unsigned char>((const unsigned char*)nmask, base, sub);
    else                  cnt = prefix_count<int>((const int*)nmask, base, sub);

    const float inv_r = 1.0f / 0.3f;
    const float eps   = 1e-12f;
    const float FOUR_OVER_PI = 1.27323954473516268615f;

    float cpx, cpy, cpz;
    if (PACKED) {
        float4 c = pv4[2 * p];
        cpx = c.x; cpy = c.y; cpz = c.z;
    } else {
        cpx = pos[p * 3 + 0]; cpy = pos[p * 3 + 1]; cpz = pos[p * 3 + 2];
    }

    float acc0 = 0.0f, acc1 = 0.0f, acc2 = 0.0f;

    for (int k = sub; k < cnt; k += LPP) {
        int idx = nidx[base + k];

        float px, py, pz, ux, uy, uz;
        if (PACKED) {
            float4 a = pv4[2 * idx];
            float4 b = pv4[2 * idx + 1];
            px = a.x; py = a.y; pz = a.z;
            ux = a.w; uy = b.x; uz = b.y;
        } else {
            px = pos[idx * 3 + 0]; py = pos[idx * 3 + 1]; pz = pos[idx * 3 + 2];
            ux = vel[idx * 3 + 0]; uy = vel[idx * 3 + 1]; uz = vel[idx * 3 + 2];
        }

        float rx = (px - cpx) * inv_r;
        float ry = (py - cpy) * inv_r;
        float rz = (pz - cpz) * inv_r;

        float sq = rx * rx + ry * ry + rz * rz;

        // window_poly6 on normalized squared distance
        float t1  = 1.0f - sq;
        float imp = fminf(fmaxf(t1 * t1 * t1, 0.0f), 1.0f);

        // ---- ball -> cylinder (volume preserving) ----
        float norm  = sqrtf(fmaxf(sq, eps));
        float sq_xy = rx * rx + ry * ry;
        float x1, y1, z1;
        if (1.25f * rz * rz > sq_xy) {
            float s_top = sqrtf(3.0f * norm / (norm + fabsf(rz)));
            x1 = rx * s_top;
            y1 = ry * s_top;
            z1 = copysignf(norm, rz);
        } else {
            float s_side = norm / sqrtf(fmaxf(sq_xy, eps));
            x1 = rx * s_side;
            y1 = ry * s_side;
            z1 = 1.5f * rz;
        }
        if (sq < eps) { x1 = rx; y1 = ry; z1 = rz; }

        // ---- cylinder -> cube (equal-area disc -> square) ----
        float sq_xy1  = x1 * x1 + y1 * y1;
        float norm_xy = sqrtf(fmaxf(sq_xy1, eps));
        float x2, y2;
        if (fabsf(y1) <= fabsf(x1)) {
            float sx     = copysignf(norm_xy, x1);
            float safe_x = (fabsf(x1) > eps) ? x1 : 1.0f;
            x2 = sx;
            y2 = sx * FOUR_OVER_PI * atanf(y1 / safe_x);
        } else {
            float sy     = copysignf(norm_xy, y1);
            float safe_y = (fabsf(y1) > eps) ? y1 : 1.0f;
            x2 = sy * FOUR_OVER_PI * atanf(x1 / safe_y);
            y2 = sy;
        }
        if (sq_xy1 < eps) { x2 = x1; y2 = y1; }

        // ---- trilinear grid coords, align_corners=True, clamped ----
        float tx = fminf(fmaxf((x2 + 1.0f) * 1.5f, 0.0f), 3.0f);
        float ty = fminf(fmaxf((y2 + 1.0f) * 1.5f, 0.0f), 3.0f);
        float tz = fminf(fmaxf((z1 + 1.0f) * 1.5f, 0.0f), 3.0f);
        float fx0 = floorf(tx), fy0 = floorf(ty), fz0 = floorf(tz);
        int xi0 = (int)fx0, yi0 = (int)fy0, zi0 = (int)fz0;
        int xi1 = min(xi0 + 1, KS - 1);
        int yi1 = min(yi0 + 1, KS - 1);
        int zi1 = min(zi0 + 1, KS - 1);
        float wx1 = tx - fx0, wx0 = 1.0f - wx1;
        float wy1 = ty - fy0, wy0 = 1.0f - wy1;
        float wz1 = tz - fz0, wz0 = 1.0f - wz1;

        float vx = ux * imp;
        float vy = uy * imp;
        float vz = uz * imp;

        int   zi[2] = { zi0, zi1 };  float wz[2] = { wz0, wz1 };
        int   yi[2] = { yi0, yi1 };  float wy[2] = { wy0, wy1 };
        int   xi[2] = { xi0, xi1 };  float wx[2] = { wx0, wx1 };

        #pragma unroll
        for (int cz = 0; cz < 2; ++cz) {
            #pragma unroll
            for (int cy = 0; cy < 2; ++cy) {
                #pragma unroll
                for (int cx = 0; cx < 2; ++cx) {
                    int corner = (zi[cz] * KS + yi[cy]) * KS + xi[cx];
                    float w = wz[cz] * wy[cy] * wx[cx];
                    const float* Wc = &Ws[corner * 12];
                    float q0 = w * vx, q1 = w * vy, q2 = w * vz;
                    acc0 += q0 * Wc[0] + q1 * Wc[3] + q2 * Wc[6];
                    acc1 += q0 * Wc[1] + q1 * Wc[4] + q2 * Wc[7];
                    acc2 += q0 * Wc[2] + q1 * Wc[5] + q2 * Wc[8];
                }
            }
        }
    }

    // reduce across the 16 lanes of this particle
    acc0 += __shfl_xor(acc0, 1); acc0 += __shfl_xor(acc0, 2);
    acc0 += __shfl_xor(acc0, 4); acc0 += __shfl_xor(acc0, 8);
    acc1 += __shfl_xor(acc1, 1); acc1 += __shfl_xor(acc1, 2);
    acc1 += __shfl_xor(acc1, 4); acc1 += __shfl_xor(acc1, 8);
    acc2 += __shfl_xor(acc2, 1); acc2 += __shfl_xor(acc2, 2);
    acc2 += __shfl_xor(acc2, 4); acc2 += __shfl_xor(acc2, 8);

    if (sub == 0) {
        out[p * 3 + 0] = acc0;
        out[p * 3 + 1] = acc1;
        out[p * 3 + 2] = acc2;
    }
}

extern "C" void kernel_launch(void* const* d_in, const int* in_sizes, int n_in,
                              void* d_out, int out_size, void* d_ws, size_t ws_size,
                              hipStream_t stream) {
    const float* pos   = (const float*)d_in[0];
    const float* vel   = (const float*)d_in[1];
    const float* Wg    = (const float*)d_in[2];
    const int*   nidx  = (const int*)d_in[3];
    const void*  nmask = d_in[4];
    float*       out   = (float*)d_out;

    int*   flag   = (int*)d_ws;
    size_t pv_off = 256;
    size_t need   = pv_off + (size_t)N_PART * 8 * sizeof(float);
    bool   packed = ws_size >= need;
    float4* pv4   = (float4*)((char*)d_ws + pv_off);

    detect_mask_kernel<<<1, 64, 0, stream>>>((const int*)nmask, flag);
    if (packed) {
        pack_pv_kernel<<<(N_PART + 255) / 256, 256, 0, stream>>>(pos, vel, pv4);
    }

    int threads = 256;
    long long total = (long long)N_PART * LPP;
    int grid = (int)((total + threads - 1) / threads);
    if (packed) {
        cconv_kernel<true><<<grid, threads, 0, stream>>>(pos, vel, pv4, Wg, nidx, nmask, flag, out);
    } else {
        cconv_kernel<false><<<grid, threads, 0, stream>>>(pos, vel, (const float4*)nullptr, Wg, nidx, nmask, flag, out);
    }
}

// Round 4
// 47.057 us; speedup vs baseline: 1.3588x; 1.0680x over previous
//
#include <hip/hip_runtime.h>
#include <math.h>

#define N_PART 50000
#define KMAX 80
#define KS 4
#define LPP 16   // lanes per particle

typedef __attribute__((ext_vector_type(8))) _Float16 h8;

// ---------------------------------------------------------------------------
// Mask-dtype detection: numpy bool may arrive as 1-byte bools or as int32.
// If any aligned int32 word is outside {0,1}, storage must be byte-bools
// (runs of consecutive True pack into 0x01010101). One wave, 512 words.
// ---------------------------------------------------------------------------
__global__ void detect_mask_kernel(const int* __restrict__ m, int* __restrict__ flag) {
    int lane = threadIdx.x;
    bool big = false;
    for (int i = lane; i < 512; i += 64) {
        int v = m[i];
        if (v > 1 || v < 0) big = true;
    }
    unsigned long long b = __ballot(big);
    if (lane == 0) flag[0] = (b != 0ULL) ? 1 : 0;   // 1 => byte-bool storage
}

// Pack [pos.xyz | vel.xyz | 0 | 0] as 32B per particle for 2x dwordx4 gathers.
__global__ __launch_bounds__(256) void pack_pv_kernel(
    const float* __restrict__ pos, const float* __restrict__ vel,
    float4* __restrict__ pv4)
{
    int p = blockIdx.x * blockDim.x + threadIdx.x;
    if (p >= N_PART) return;
    float4 a = make_float4(pos[3*p], pos[3*p+1], pos[3*p+2], vel[3*p]);
    float4 b = make_float4(vel[3*p+1], vel[3*p+2], 0.0f, 0.0f);
    pv4[2*p]     = a;
    pv4[2*p + 1] = b;
}

// Count the true-prefix length of row p using this particle's 16 lanes.
template <typename MT>
__device__ __forceinline__ int prefix_count(const MT* __restrict__ nmask, int base, int sub) {
    int lc = 0; bool more = true;
    #pragma unroll
    for (int i = 0; i < 5; ++i) {
        bool t = nmask[base + sub * 5 + i] != 0;
        lc += (more && t) ? 1 : 0;
        more = more && t;
    }
    bool full = (lc == 5);
    unsigned long long nb = __ballot(!full);
    int wl  = threadIdx.x & 63;
    int grp = wl >> 4;
    unsigned int gb = (unsigned int)((nb >> (16 * grp)) & 0xFFFFull);
    if (gb == 0) return KMAX;
    int fi  = __ffs(gb) - 1;
    int flc = __shfl(lc, (grp << 4) + fi, 64);
    return fi * 5 + flc;
}

template <bool PACKED>
__global__ __launch_bounds__(256) void cconv_kernel(
    const float* __restrict__ pos,
    const float* __restrict__ vel,
    const float4* __restrict__ pv4,    // packed [pos|vel], valid if PACKED
    const float* __restrict__ Wg,      // [64*3*3] (g, cin, cout)
    const int* __restrict__ nidx,      // [N][KMAX]
    const void* __restrict__ nmask,    // [N][KMAX], dtype per flag
    const int* __restrict__ maskFlag,  // 1 => byte-bool, 0 => int32
    float* __restrict__ out)           // [N][3]
{
    // W in LDS as fp16, one corner = 16 halves (32B): ds_read_b128 + ds_read_u16.
    __shared__ _Float16 WsH[64 * 16];
    for (int t = threadIdx.x; t < 64 * 16; t += blockDim.x) {
        int g = t >> 4, r = t & 15;
        WsH[t] = (r < 9) ? (_Float16)Wg[g * 9 + r] : (_Float16)0.0f;
    }
    __syncthreads();

    int gid = blockIdx.x * blockDim.x + threadIdx.x;
    int p   = gid / LPP;
    int sub = gid & (LPP - 1);
    if (p >= N_PART) return;

    const int base = p * KMAX;

    int cnt;
    if (maskFlag[0] != 0) cnt = prefix_count<unsigned char>((const unsigned char*)nmask, base, sub);
    else                  cnt = prefix_count<int>((const int*)nmask, base, sub);

    const float inv_r = 1.0f / 0.3f;
    const float eps   = 1e-12f;
    const float FOUR_OVER_PI = 1.27323954473516268615f;

    float cpx, cpy, cpz;
    if (PACKED) {
        float4 c = pv4[2 * p];
        cpx = c.x; cpy = c.y; cpz = c.z;
    } else {
        cpx = pos[p * 3 + 0]; cpy = pos[p * 3 + 1]; cpz = pos[p * 3 + 2];
    }

    float acc0 = 0.0f, acc1 = 0.0f, acc2 = 0.0f;

    for (int k = sub; k < cnt; k += LPP) {
        int idx = nidx[base + k];

        float px, py, pz, ux, uy, uz;
        if (PACKED) {
            float4 a = pv4[2 * idx];
            float4 b = pv4[2 * idx + 1];
            px = a.x; py = a.y; pz = a.z;
            ux = a.w; uy = b.x; uz = b.y;
        } else {
            px = pos[idx * 3 + 0]; py = pos[idx * 3 + 1]; pz = pos[idx * 3 + 2];
            ux = vel[idx * 3 + 0]; uy = vel[idx * 3 + 1]; uz = vel[idx * 3 + 2];
        }

        float rx = (px - cpx) * inv_r;
        float ry = (py - cpy) * inv_r;
        float rz = (pz - cpz) * inv_r;

        float sq = rx * rx + ry * ry + rz * rz;

        // window_poly6 on normalized squared distance
        float t1  = 1.0f - sq;
        float imp = fminf(fmaxf(t1 * t1 * t1, 0.0f), 1.0f);

        // ---- ball -> cylinder (volume preserving) ----
        float norm  = sqrtf(fmaxf(sq, eps));
        float sq_xy = rx * rx + ry * ry;
        float x1, y1, z1;
        if (1.25f * rz * rz > sq_xy) {
            float s_top = sqrtf(3.0f * norm / (norm + fabsf(rz)));
            x1 = rx * s_top;
            y1 = ry * s_top;
            z1 = copysignf(norm, rz);
        } else {
            float s_side = norm / sqrtf(fmaxf(sq_xy, eps));
            x1 = rx * s_side;
            y1 = ry * s_side;
            z1 = 1.5f * rz;
        }
        if (sq < eps) { x1 = rx; y1 = ry; z1 = rz; }

        // ---- cylinder -> cube (equal-area disc -> square) ----
        float sq_xy1  = x1 * x1 + y1 * y1;
        float norm_xy = sqrtf(fmaxf(sq_xy1, eps));
        float x2, y2;
        if (fabsf(y1) <= fabsf(x1)) {
            float sx     = copysignf(norm_xy, x1);
            float safe_x = (fabsf(x1) > eps) ? x1 : 1.0f;
            x2 = sx;
            y2 = sx * FOUR_OVER_PI * atanf(y1 / safe_x);
        } else {
            float sy     = copysignf(norm_xy, y1);
            float safe_y = (fabsf(y1) > eps) ? y1 : 1.0f;
            x2 = sy * FOUR_OVER_PI * atanf(x1 / safe_y);
            y2 = sy;
        }
        if (sq_xy1 < eps) { x2 = x1; y2 = y1; }

        // ---- trilinear grid coords, align_corners=True, clamped ----
        float tx = fminf(fmaxf((x2 + 1.0f) * 1.5f, 0.0f), 3.0f);
        float ty = fminf(fmaxf((y2 + 1.0f) * 1.5f, 0.0f), 3.0f);
        float tz = fminf(fmaxf((z1 + 1.0f) * 1.5f, 0.0f), 3.0f);
        float fx0 = floorf(tx), fy0 = floorf(ty), fz0 = floorf(tz);
        int xi0 = (int)fx0, yi0 = (int)fy0, zi0 = (int)fz0;
        int xi1 = min(xi0 + 1, KS - 1);
        int yi1 = min(yi0 + 1, KS - 1);
        int zi1 = min(zi0 + 1, KS - 1);
        float wx1 = tx - fx0, wx0 = 1.0f - wx1;
        float wy1 = ty - fy0, wy0 = 1.0f - wy1;
        float wz1 = tz - fz0, wz0 = 1.0f - wz1;

        float vx = ux * imp;
        float vy = uy * imp;
        float vz = uz * imp;

        int   zi[2] = { zi0, zi1 };  float wz[2] = { wz0, wz1 };
        int   yi[2] = { yi0, yi1 };  float wy[2] = { wy0, wy1 };
        int   xi[2] = { xi0, xi1 };  float wx[2] = { wx0, wx1 };

        #pragma unroll
        for (int cz = 0; cz < 2; ++cz) {
            #pragma unroll
            for (int cy = 0; cy < 2; ++cy) {
                #pragma unroll
                for (int cx = 0; cx < 2; ++cx) {
                    int corner = (zi[cz] * KS + yi[cy]) * KS + xi[cx];
                    const _Float16* Wc = &WsH[corner << 4];
                    h8    wv  = *(const h8*)Wc;   // ds_read_b128: W[g][0..7]
                    float w8f = (float)Wc[8];     // ds_read_u16:  W[g][8]
                    float w  = wz[cz] * wy[cy] * wx[cx];
                    float q0 = w * vx, q1 = w * vy, q2 = w * vz;
                    acc0 += q0 * (float)wv[0] + q1 * (float)wv[3] + q2 * (float)wv[6];
                    acc1 += q0 * (float)wv[1] + q1 * (float)wv[4] + q2 * (float)wv[7];
                    acc2 += q0 * (float)wv[2] + q1 * (float)wv[5] + q2 * w8f;
                }
            }
        }
    }

    // reduce across the 16 lanes of this particle
    acc0 += __shfl_xor(acc0, 1); acc0 += __shfl_xor(acc0, 2);
    acc0 += __shfl_xor(acc0, 4); acc0 += __shfl_xor(acc0, 8);
    acc1 += __shfl_xor(acc1, 1); acc1 += __shfl_xor(acc1, 2);
    acc1 += __shfl_xor(acc1, 4); acc1 += __shfl_xor(acc1, 8);
    acc2 += __shfl_xor(acc2, 1); acc2 += __shfl_xor(acc2, 2);
    acc2 += __shfl_xor(acc2, 4); acc2 += __shfl_xor(acc2, 8);

    if (sub == 0) {
        out[p * 3 + 0] = acc0;
        out[p * 3 + 1] = acc1;
        out[p * 3 + 2] = acc2;
    }
}

extern "C" void kernel_launch(void* const* d_in, const int* in_sizes, int n_in,
                              void* d_out, int out_size, void* d_ws, size_t ws_size,
                              hipStream_t stream) {
    const float* pos   = (const float*)d_in[0];
    const float* vel   = (const float*)d_in[1];
    const float* Wg    = (const float*)d_in[2];
    const int*   nidx  = (const int*)d_in[3];
    const void*  nmask = d_in[4];
    float*       out   = (float*)d_out;

    int*   flag   = (int*)d_ws;
    size_t pv_off = 256;
    size_t need   = pv_off + (size_t)N_PART * 8 * sizeof(float);
    bool   packed = ws_size >= need;
    float4* pv4   = (float4*)((char*)d_ws + pv_off);

    detect_mask_kernel<<<1, 64, 0, stream>>>((const int*)nmask, flag);
    if (packed) {
        pack_pv_kernel<<<(N_PART + 255) / 256, 256, 0, stream>>>(pos, vel, pv4);
    }

    int threads = 256;
    long long total = (long long)N_PART * LPP;
    int grid = (int)((total + threads - 1) / threads);
    if (packed) {
        cconv_kernel<true><<<grid, threads, 0, stream>>>(pos, vel, pv4, Wg, nidx, nmask, flag, out);
    } else {
        cconv_kernel<false><<<grid, threads, 0, stream>>>(pos, vel, (const float4*)nullptr, Wg, nidx, nmask, flag, out);
    }
}

// Round 5
// 46.504 us; speedup vs baseline: 1.3749x; 1.0119x over previous
//
#include <hip/hip_runtime.h>
#include <math.h>

#define N_PART 50000
#define KMAX 80
#define KS 4
#define LPP 16   // lanes per particle

typedef __attribute__((ext_vector_type(8))) _Float16 h8;

// ---------------------------------------------------------------------------
// Mask-dtype detection: numpy bool may arrive as 1-byte bools or as int32.
// If any aligned int32 word is outside {0,1}, storage must be byte-bools.
// ---------------------------------------------------------------------------
__global__ void detect_mask_kernel(const int* __restrict__ m, int* __restrict__ flag) {
    int lane = threadIdx.x;
    bool big = false;
    for (int i = lane; i < 512; i += 64) {
        int v = m[i];
        if (v > 1 || v < 0) big = true;
    }
    unsigned long long b = __ballot(big);
    if (lane == 0) flag[0] = (b != 0ULL) ? 1 : 0;   // 1 => byte-bool storage
}

// Pack [pos.xyz | vel.xyz | 0 | 0] as 32B per particle for 2x dwordx4 gathers.
__global__ __launch_bounds__(256) void pack_pv_kernel(
    const float* __restrict__ pos, const float* __restrict__ vel,
    float4* __restrict__ pv4)
{
    int p = blockIdx.x * blockDim.x + threadIdx.x;
    if (p >= N_PART) return;
    float4 a = make_float4(pos[3*p], pos[3*p+1], pos[3*p+2], vel[3*p]);
    float4 b = make_float4(vel[3*p+1], vel[3*p+2], 0.0f, 0.0f);
    pv4[2*p]     = a;
    pv4[2*p + 1] = b;
}

// Count the true-prefix length of row p using this particle's 16 lanes.
template <typename MT>
__device__ __forceinline__ int prefix_count(const MT* __restrict__ nmask, int base, int sub) {
    int lc = 0; bool more = true;
    #pragma unroll
    for (int i = 0; i < 5; ++i) {
        bool t = nmask[base + sub * 5 + i] != 0;
        lc += (more && t) ? 1 : 0;
        more = more && t;
    }
    bool full = (lc == 5);
    unsigned long long nb = __ballot(!full);
    int wl  = threadIdx.x & 63;
    int grp = wl >> 4;
    unsigned int gb = (unsigned int)((nb >> (16 * grp)) & 0xFFFFull);
    if (gb == 0) return KMAX;
    int fi  = __ffs(gb) - 1;
    int flc = __shfl(lc, (grp << 4) + fi, 64);
    return fi * 5 + flc;
}

// minimax odd polynomial for atan(t), t in [-1,1]; max abs err ~1e-5
__device__ __forceinline__ float atan_poly(float t) {
    float t2 = t * t;
    float p = -0.01172120f;
    p = p * t2 + 0.05265332f;
    p = p * t2 - 0.11643287f;
    p = p * t2 + 0.19354346f;
    p = p * t2 - 0.33262347f;
    p = p * t2 + 0.99997726f;
    return t * p;
}

template <bool PACKED>
__global__ __launch_bounds__(256) void cconv_kernel(
    const float* __restrict__ pos,
    const float* __restrict__ vel,
    const float4* __restrict__ pv4,    // packed [pos|vel], valid if PACKED
    const float* __restrict__ Wg,      // [64*3*3] (g, cin, cout)
    const int* __restrict__ nidx,      // [N][KMAX]
    const void* __restrict__ nmask,    // [N][KMAX], dtype per flag
    const int* __restrict__ maskFlag,  // 1 => byte-bool, 0 => int32
    float* __restrict__ out)           // [N][3]
{
    // W[c][0..7] in LDS as fp16 (exactly one ds_read_b128 per corner);
    // W[c][8] is read from global Wg (L1-resident 2.3KB table, TA pipe).
    __shared__ _Float16 WsH[64 * 8];
    for (int t = threadIdx.x; t < 64 * 8; t += blockDim.x) {
        int g = t >> 3, r = t & 7;
        WsH[t] = (_Float16)Wg[g * 9 + r];
    }
    __syncthreads();

    int gid = blockIdx.x * blockDim.x + threadIdx.x;
    int p   = gid / LPP;
    int sub = gid & (LPP - 1);
    if (p >= N_PART) return;

    const int base = p * KMAX;

    int cnt;
    if (maskFlag[0] != 0) cnt = prefix_count<unsigned char>((const unsigned char*)nmask, base, sub);
    else                  cnt = prefix_count<int>((const int*)nmask, base, sub);

    const float inv_r = 1.0f / 0.3f;
    const float eps   = 1e-12f;
    const float FOUR_OVER_PI = 1.27323954473516268615f;

    float cpx, cpy, cpz;
    if (PACKED) {
        float4 c = pv4[2 * p];
        cpx = c.x; cpy = c.y; cpz = c.z;
    } else {
        cpx = pos[p * 3 + 0]; cpy = pos[p * 3 + 1]; cpz = pos[p * 3 + 2];
    }

    float acc0 = 0.0f, acc1 = 0.0f, acc2 = 0.0f;

    for (int k = sub; k < cnt; k += LPP) {
        int idx = nidx[base + k];

        float px, py, pz, ux, uy, uz;
        if (PACKED) {
            float4 a = pv4[2 * idx];
            float4 b = pv4[2 * idx + 1];
            px = a.x; py = a.y; pz = a.z;
            ux = a.w; uy = b.x; uz = b.y;
        } else {
            px = pos[idx * 3 + 0]; py = pos[idx * 3 + 1]; pz = pos[idx * 3 + 2];
            ux = vel[idx * 3 + 0]; uy = vel[idx * 3 + 1]; uz = vel[idx * 3 + 2];
        }

        float rx = (px - cpx) * inv_r;
        float ry = (py - cpy) * inv_r;
        float rz = (pz - cpz) * inv_r;

        float sq = rx * rx + ry * ry + rz * rz;

        // window_poly6 on normalized squared distance
        float t1  = 1.0f - sq;
        float imp = fminf(fmaxf(t1 * t1 * t1, 0.0f), 1.0f);

        // ---- ball -> cylinder (volume preserving), branch-lite ----
        float norm  = sqrtf(fmaxf(sq, eps));
        float sq_xy = rx * rx + ry * ry;
        bool  top   = (1.25f * rz * rz) > sq_xy;
        float s_top  = sqrtf(3.0f * norm * __builtin_amdgcn_rcpf(norm + fabsf(rz)));
        float s_side = norm * __builtin_amdgcn_rsqf(fmaxf(sq_xy, eps));
        float s  = top ? s_top : s_side;
        float x1 = rx * s;
        float y1 = ry * s;
        float z1 = top ? copysignf(norm, rz) : 1.5f * rz;
        if (sq < eps) { x1 = rx; y1 = ry; z1 = rz; }

        // ---- cylinder -> cube (equal-area disc -> square) ----
        float sq_xy1  = x1 * x1 + y1 * y1;
        float norm_xy = sqrtf(fmaxf(sq_xy1, eps));
        bool  xbig = fabsf(y1) <= fabsf(x1);
        float num  = xbig ? y1 : x1;
        float den  = xbig ? x1 : y1;
        float sden = (fabsf(den) > eps) ? den : 1.0f;
        float t    = num * __builtin_amdgcn_rcpf(sden);
        float at   = atan_poly(t);
        float sd   = copysignf(norm_xy, den);
        float u    = sd * FOUR_OVER_PI * at;
        float x2   = xbig ? sd : u;
        float y2   = xbig ? u  : sd;
        if (sq_xy1 < eps) { x2 = x1; y2 = y1; }

        // ---- trilinear grid coords, align_corners=True, clamped ----
        float tx = fminf(fmaxf((x2 + 1.0f) * 1.5f, 0.0f), 3.0f);
        float ty = fminf(fmaxf((y2 + 1.0f) * 1.5f, 0.0f), 3.0f);
        float tz = fminf(fmaxf((z1 + 1.0f) * 1.5f, 0.0f), 3.0f);
        float fx0 = floorf(tx), fy0 = floorf(ty), fz0 = floorf(tz);
        int xi0 = (int)fx0, yi0 = (int)fy0, zi0 = (int)fz0;
        int xi1 = min(xi0 + 1, KS - 1);
        int yi1 = min(yi0 + 1, KS - 1);
        int zi1 = min(zi0 + 1, KS - 1);
        float wx1 = tx - fx0, wx0 = 1.0f - wx1;
        float wy1 = ty - fy0, wy0 = 1.0f - wy1;
        float wz1 = tz - fz0, wz0 = 1.0f - wz1;

        float vx = ux * imp;
        float vy = uy * imp;
        float vz = uz * imp;

        int   zi[2] = { zi0, zi1 };  float wz[2] = { wz0, wz1 };
        int   yi[2] = { yi0, yi1 };  float wy[2] = { wy0, wy1 };
        int   xi[2] = { xi0, xi1 };  float wx[2] = { wx0, wx1 };

        #pragma unroll
        for (int cz = 0; cz < 2; ++cz) {
            #pragma unroll
            for (int cy = 0; cy < 2; ++cy) {
                #pragma unroll
                for (int cx = 0; cx < 2; ++cx) {
                    int corner = (zi[cz] * KS + yi[cy]) * KS + xi[cx];
                    h8    wv = *(const h8*)&WsH[corner << 3];  // ds_read_b128
                    float w9 = Wg[corner * 9 + 8];             // global, L1-hot
                    float w  = wz[cz] * wy[cy] * wx[cx];
                    float q0 = w * vx, q1 = w * vy, q2 = w * vz;
                    acc0 += q0 * (float)wv[0] + q1 * (float)wv[3] + q2 * (float)wv[6];
                    acc1 += q0 * (float)wv[1] + q1 * (float)wv[4] + q2 * (float)wv[7];
                    acc2 += q0 * (float)wv[2] + q1 * (float)wv[5] + q2 * w9;
                }
            }
        }
    }

    // reduce across the 16 lanes of this particle
    acc0 += __shfl_xor(acc0, 1); acc0 += __shfl_xor(acc0, 2);
    acc0 += __shfl_xor(acc0, 4); acc0 += __shfl_xor(acc0, 8);
    acc1 += __shfl_xor(acc1, 1); acc1 += __shfl_xor(acc1, 2);
    acc1 += __shfl_xor(acc1, 4); acc1 += __shfl_xor(acc1, 8);
    acc2 += __shfl_xor(acc2, 1); acc2 += __shfl_xor(acc2, 2);
    acc2 += __shfl_xor(acc2, 4); acc2 += __shfl_xor(acc2, 8);

    if (sub == 0) {
        out[p * 3 + 0] = acc0;
        out[p * 3 + 1] = acc1;
        out[p * 3 + 2] = acc2;
    }
}

extern "C" void kernel_launch(void* const* d_in, const int* in_sizes, int n_in,
                              void* d_out, int out_size, void* d_ws, size_t ws_size,
                              hipStream_t stream) {
    const float* pos   = (const float*)d_in[0];
    const float* vel   = (const float*)d_in[1];
    const float* Wg    = (const float*)d_in[2];
    const int*   nidx  = (const int*)d_in[3];
    const void*  nmask = d_in[4];
    float*       out   = (float*)d_out;

    int*   flag   = (int*)d_ws;
    size_t pv_off = 256;
    size_t need   = pv_off + (size_t)N_PART * 8 * sizeof(float);
    bool   packed = ws_size >= need;
    float4* pv4   = (float4*)((char*)d_ws + pv_off);

    detect_mask_kernel<<<1, 64, 0, stream>>>((const int*)nmask, flag);
    if (packed) {
        pack_pv_kernel<<<(N_PART + 255) / 256, 256, 0, stream>>>(pos, vel, pv4);
    }

    int threads = 256;
    long long total = (long long)N_PART * LPP;
    int grid = (int)((total + threads - 1) / threads);
    if (packed) {
        cconv_kernel<true><<<grid, threads, 0, stream>>>(pos, vel, pv4, Wg, nidx, nmask, flag, out);
    } else {
        cconv_kernel<false><<<grid, threads, 0, stream>>>(pos, vel, (const float4*)nullptr, Wg, nidx, nmask, flag, out);
    }
}

// Round 6
// 36.562 us; speedup vs baseline: 1.7488x; 1.2719x over previous
//
#include <hip/hip_runtime.h>
#include <math.h>

#define N_PART 50000
#define KMAX 80
#define KS 4
#define LPP 16   // lanes per particle

typedef __attribute__((ext_vector_type(8))) _Float16 h8;
typedef __attribute__((ext_vector_type(2))) _Float16 h2;

// ---------------------------------------------------------------------------
// Mask-dtype detection: numpy bool may arrive as 1-byte bools or as int32.
// ---------------------------------------------------------------------------
__global__ void detect_mask_kernel(const int* __restrict__ m, int* __restrict__ flag) {
    int lane = threadIdx.x;
    bool big = false;
    for (int i = lane; i < 512; i += 64) {
        int v = m[i];
        if (v > 1 || v < 0) big = true;
    }
    unsigned long long b = __ballot(big);
    if (lane == 0) flag[0] = (b != 0ULL) ? 1 : 0;   // 1 => byte-bool storage
}

// Pack [pos.xyz | vel.xyz | 0 | 0] as 32B per particle for 2x dwordx4 gathers.
__global__ __launch_bounds__(256) void pack_pv_kernel(
    const float* __restrict__ pos, const float* __restrict__ vel,
    float4* __restrict__ pv4)
{
    int p = blockIdx.x * blockDim.x + threadIdx.x;
    if (p >= N_PART) return;
    float4 a = make_float4(pos[3*p], pos[3*p+1], pos[3*p+2], vel[3*p]);
    float4 b = make_float4(vel[3*p+1], vel[3*p+2], 0.0f, 0.0f);
    pv4[2*p]     = a;
    pv4[2*p + 1] = b;
}

// Count the true-prefix length of row p using this particle's 16 lanes.
template <typename MT>
__device__ __forceinline__ int prefix_count(const MT* __restrict__ nmask, int base, int sub) {
    int lc = 0; bool more = true;
    #pragma unroll
    for (int i = 0; i < 5; ++i) {
        bool t = nmask[base + sub * 5 + i] != 0;
        lc += (more && t) ? 1 : 0;
        more = more && t;
    }
    bool full = (lc == 5);
    unsigned long long nb = __ballot(!full);
    int wl  = threadIdx.x & 63;
    int grp = wl >> 4;
    unsigned int gb = (unsigned int)((nb >> (16 * grp)) & 0xFFFFull);
    if (gb == 0) return KMAX;
    int fi  = __ffs(gb) - 1;
    int flc = __shfl(lc, (grp << 4) + fi, 64);
    return fi * 5 + flc;
}

// minimax odd polynomial for atan(t), t in [-1,1]; max abs err ~1e-5
__device__ __forceinline__ float atan_poly(float t) {
    float t2 = t * t;
    float p = -0.01172120f;
    p = p * t2 + 0.05265332f;
    p = p * t2 - 0.11643287f;
    p = p * t2 + 0.19354346f;
    p = p * t2 - 0.33262347f;
    p = p * t2 + 0.99997726f;
    return t * p;
}

template <bool PACKED>
__global__ __launch_bounds__(256) void cconv_kernel(
    const float* __restrict__ pos,
    const float* __restrict__ vel,
    const float4* __restrict__ pv4,    // packed [pos|vel], valid if PACKED
    const float* __restrict__ Wg,      // [64*3*3] (g, cin, cout)
    const int* __restrict__ nidx,      // [N][KMAX]
    const void* __restrict__ nmask,    // [N][KMAX], dtype per flag
    const int* __restrict__ maskFlag,  // 1 => byte-bool, 0 => int32
    float* __restrict__ out)           // [N][3]
{
    // W[c][0..7] as fp16 (one ds_read_b128/corner), W[c][8] as f32 (ds_read_b32).
    __shared__ _Float16 WsH[64 * 8];
    __shared__ float    Ws8[64];
    for (int t = threadIdx.x; t < 64 * 8; t += blockDim.x) {
        int g = t >> 3, r = t & 7;
        WsH[t] = (_Float16)Wg[g * 9 + r];
    }
    for (int t = threadIdx.x; t < 64; t += blockDim.x)
        Ws8[t] = Wg[t * 9 + 8];
    __syncthreads();

    int gid = blockIdx.x * blockDim.x + threadIdx.x;
    int p   = gid / LPP;
    int sub = gid & (LPP - 1);
    if (p >= N_PART) return;

    const int base = p * KMAX;

    // Issue the first gather immediately (independent of the mask scan).
    int    idx0 = nidx[base + sub];
    float4 a, b;
    float  cpx, cpy, cpz;
    if (PACKED) {
        a = pv4[2 * idx0];
        b = pv4[2 * idx0 + 1];
        float4 c = pv4[2 * p];
        cpx = c.x; cpy = c.y; cpz = c.z;
    } else {
        a = make_float4(pos[idx0*3], pos[idx0*3+1], pos[idx0*3+2], vel[idx0*3]);
        b = make_float4(vel[idx0*3+1], vel[idx0*3+2], 0.f, 0.f);
        cpx = pos[p * 3 + 0]; cpy = pos[p * 3 + 1]; cpz = pos[p * 3 + 2];
    }

    int cnt;
    if (maskFlag[0] != 0) cnt = prefix_count<unsigned char>((const unsigned char*)nmask, base, sub);
    else                  cnt = prefix_count<int>((const int*)nmask, base, sub);

    const float inv_r = 1.0f / 0.3f;
    const float eps   = 1e-12f;
    const float FOUR_OVER_PI = 1.27323954473516268615f;

    float acc0 = 0.0f, acc1 = 0.0f, acc2 = 0.0f;

    for (int k = sub; k < cnt; k += LPP) {
        // ---- prefetch next trip's gather (hides L2/L3 latency under math) ----
        int    kn   = min(k + LPP, KMAX - 1);
        int    idxn = nidx[base + kn];
        float4 an, bn;
        if (PACKED) {
            an = pv4[2 * idxn];
            bn = pv4[2 * idxn + 1];
        } else {
            an = make_float4(pos[idxn*3], pos[idxn*3+1], pos[idxn*3+2], vel[idxn*3]);
            bn = make_float4(vel[idxn*3+1], vel[idxn*3+2], 0.f, 0.f);
        }

        float rx = (a.x - cpx) * inv_r;
        float ry = (a.y - cpy) * inv_r;
        float rz = (a.z - cpz) * inv_r;
        float ux = a.w, uy = b.x, uz = b.y;

        float sq = rx * rx + ry * ry + rz * rz;

        // window_poly6 on normalized squared distance
        float t1  = 1.0f - sq;
        float imp = fminf(fmaxf(t1 * t1 * t1, 0.0f), 1.0f);

        // ---- ball -> cylinder (volume preserving), branch-lite ----
        float norm  = sqrtf(fmaxf(sq, eps));
        float sq_xy = rx * rx + ry * ry;
        bool  top   = (1.25f * rz * rz) > sq_xy;
        float s_top  = sqrtf(3.0f * norm * __builtin_amdgcn_rcpf(norm + fabsf(rz)));
        float s_side = norm * __builtin_amdgcn_rsqf(fmaxf(sq_xy, eps));
        float s  = top ? s_top : s_side;
        float x1 = rx * s;
        float y1 = ry * s;
        float z1 = top ? copysignf(norm, rz) : 1.5f * rz;
        if (sq < eps) { x1 = rx; y1 = ry; z1 = rz; }

        // ---- cylinder -> cube (equal-area disc -> square) ----
        float sq_xy1  = x1 * x1 + y1 * y1;
        float norm_xy = sqrtf(fmaxf(sq_xy1, eps));
        bool  xbig = fabsf(y1) <= fabsf(x1);
        float num  = xbig ? y1 : x1;
        float den  = xbig ? x1 : y1;
        float sden = (fabsf(den) > eps) ? den : 1.0f;
        float t    = num * __builtin_amdgcn_rcpf(sden);
        float at   = atan_poly(t);
        float sd   = copysignf(norm_xy, den);
        float u    = sd * FOUR_OVER_PI * at;
        float x2   = xbig ? sd : u;
        float y2   = xbig ? u  : sd;
        if (sq_xy1 < eps) { x2 = x1; y2 = y1; }

        // ---- trilinear grid coords, align_corners=True, clamped ----
        float tx = fminf(fmaxf((x2 + 1.0f) * 1.5f, 0.0f), 3.0f);
        float ty = fminf(fmaxf((y2 + 1.0f) * 1.5f, 0.0f), 3.0f);
        float tz = fminf(fmaxf((z1 + 1.0f) * 1.5f, 0.0f), 3.0f);
        float fx0 = floorf(tx), fy0 = floorf(ty), fz0 = floorf(tz);
        int xi0 = (int)fx0, yi0 = (int)fy0, zi0 = (int)fz0;
        int xi1 = min(xi0 + 1, KS - 1);
        int yi1 = min(yi0 + 1, KS - 1);
        int zi1 = min(zi0 + 1, KS - 1);
        float wx1 = tx - fx0, wx0 = 1.0f - wx1;
        float wy1 = ty - fy0, wy0 = 1.0f - wy1;
        float wz1 = tz - fz0, wz0 = 1.0f - wz1;

        int   zi[2] = { zi0, zi1 };  float wzv[2] = { wz0, wz1 };
        int   yi[2] = { yi0, yi1 };  float wyv[2] = { wy0, wy1 };
        int   xi[2] = { xi0, xi1 };  float wxv[2] = { wx0, wx1 };

        // ---- per-pair M = sum_c w_c * W_c, accumulated in packed fp16 ----
        h2 M01 = (h2)(_Float16)0.0f;
        h2 M23 = (h2)(_Float16)0.0f;
        h2 M45 = (h2)(_Float16)0.0f;
        h2 M67 = (h2)(_Float16)0.0f;
        float m8 = 0.0f;

        #pragma unroll
        for (int cz = 0; cz < 2; ++cz) {
            #pragma unroll
            for (int cy = 0; cy < 2; ++cy) {
                #pragma unroll
                for (int cx = 0; cx < 2; ++cx) {
                    int corner = (zi[cz] * KS + yi[cy]) * KS + xi[cx];
                    h8 wv = *(const h8*)&WsH[corner << 3];   // ds_read_b128
                    float wf = wzv[cz] * wyv[cy] * wxv[cx];
                    _Float16 wh = (_Float16)wf;
                    h2 ww = { wh, wh };
                    M01 += ww * __builtin_shufflevector(wv, wv, 0, 1);
                    M23 += ww * __builtin_shufflevector(wv, wv, 2, 3);
                    M45 += ww * __builtin_shufflevector(wv, wv, 4, 5);
                    M67 += ww * __builtin_shufflevector(wv, wv, 6, 7);
                    m8  += wf * Ws8[corner];                 // ds_read_b32
                }
            }
        }

        // ---- fold: acc += imp * (M^T u);  M layout = [cin*3+cout], m8 = M[2][2]
        float m0 = (float)M01[0], m1 = (float)M01[1];
        float m2 = (float)M23[0], m3 = (float)M23[1];
        float m4 = (float)M45[0], m5 = (float)M45[1];
        float m6 = (float)M67[0], m7 = (float)M67[1];
        float s0 = ux * m0 + uy * m3 + uz * m6;
        float s1 = ux * m1 + uy * m4 + uz * m7;
        float s2 = ux * m2 + uy * m5 + uz * m8;
        acc0 += imp * s0;
        acc1 += imp * s1;
        acc2 += imp * s2;

        a = an; b = bn;
    }

    // reduce across the 16 lanes of this particle
    acc0 += __shfl_xor(acc0, 1); acc0 += __shfl_xor(acc0, 2);
    acc0 += __shfl_xor(acc0, 4); acc0 += __shfl_xor(acc0, 8);
    acc1 += __shfl_xor(acc1, 1); acc1 += __shfl_xor(acc1, 2);
    acc1 += __shfl_xor(acc1, 4); acc1 += __shfl_xor(acc1, 8);
    acc2 += __shfl_xor(acc2, 1); acc2 += __shfl_xor(acc2, 2);
    acc2 += __shfl_xor(acc2, 4); acc2 += __shfl_xor(acc2, 8);

    if (sub == 0) {
        out[p * 3 + 0] = acc0;
        out[p * 3 + 1] = acc1;
        out[p * 3 + 2] = acc2;
    }
}

extern "C" void kernel_launch(void* const* d_in, const int* in_sizes, int n_in,
                              void* d_out, int out_size, void* d_ws, size_t ws_size,
                              hipStream_t stream) {
    const float* pos   = (const float*)d_in[0];
    const float* vel   = (const float*)d_in[1];
    const float* Wg    = (const float*)d_in[2];
    const int*   nidx  = (const int*)d_in[3];
    const void*  nmask = d_in[4];
    float*       out   = (float*)d_out;

    int*   flag   = (int*)d_ws;
    size_t pv_off = 256;
    size_t need   = pv_off + (size_t)N_PART * 8 * sizeof(float);
    bool   packed = ws_size >= need;
    float4* pv4   = (float4*)((char*)d_ws + pv_off);

    detect_mask_kernel<<<1, 64, 0, stream>>>((const int*)nmask, flag);
    if (packed) {
        pack_pv_kernel<<<(N_PART + 255) / 256, 256, 0, stream>>>(pos, vel, pv4);
    }

    int threads = 256;
    long long total = (long long)N_PART * LPP;
    int grid = (int)((total + threads - 1) / threads);
    if (packed) {
        cconv_kernel<true><<<grid, threads, 0, stream>>>(pos, vel, pv4, Wg, nidx, nmask, flag, out);
    } else {
        cconv_kernel<false><<<grid, threads, 0, stream>>>(pos, vel, (const float4*)nullptr, Wg, nidx, nmask, flag, out);
    }
}

// Round 7
// 33.772 us; speedup vs baseline: 1.8933x; 1.0826x over previous
//
#include <hip/hip_runtime.h>
#include <math.h>

#define N_PART 50000
#define KMAX 80
#define KS 4
#define LPP 16   // lanes per particle
#define MAXTRIP 5

typedef __attribute__((ext_vector_type(8))) _Float16 h8;
typedef __attribute__((ext_vector_type(2))) _Float16 h2;

// Pack [pos.xyz | vel.xyz | 0 | 0] as 32B per particle for 2x dwordx4 gathers.
__global__ __launch_bounds__(256) void pack_pv_kernel(
    const float* __restrict__ pos, const float* __restrict__ vel,
    float4* __restrict__ pv4)
{
    int p = blockIdx.x * blockDim.x + threadIdx.x;
    if (p >= N_PART) return;
    float4 a = make_float4(pos[3*p], pos[3*p+1], pos[3*p+2], vel[3*p]);
    float4 b = make_float4(vel[3*p+1], vel[3*p+2], 0.0f, 0.0f);
    pv4[2*p]     = a;
    pv4[2*p + 1] = b;
}

// Count the true-prefix length of row p using this particle's 16 lanes.
template <typename MT>
__device__ __forceinline__ int prefix_count(const MT* __restrict__ nmask, int base, int sub) {
    int lc = 0; bool more = true;
    #pragma unroll
    for (int i = 0; i < 5; ++i) {
        bool t = nmask[base + sub * 5 + i] != 0;
        lc += (more && t) ? 1 : 0;
        more = more && t;
    }
    bool full = (lc == 5);
    unsigned long long nb = __ballot(!full);
    int wl  = threadIdx.x & 63;
    int grp = wl >> 4;
    unsigned int gb = (unsigned int)((nb >> (16 * grp)) & 0xFFFFull);
    if (gb == 0) return KMAX;
    int fi  = __ffs(gb) - 1;
    int flc = __shfl(lc, (grp << 4) + fi, 64);
    return fi * 5 + flc;
}

// minimax odd polynomial for atan(t), t in [-1,1]; max abs err ~1e-5
__device__ __forceinline__ float atan_poly(float t) {
    float t2 = t * t;
    float p = -0.01172120f;
    p = p * t2 + 0.05265332f;
    p = p * t2 - 0.11643287f;
    p = p * t2 + 0.19354346f;
    p = p * t2 - 0.33262347f;
    p = p * t2 + 0.99997726f;
    return t * p;
}

template <bool PACKED>
__global__ __launch_bounds__(256) void cconv_kernel(
    const float* __restrict__ pos,
    const float* __restrict__ vel,
    const float4* __restrict__ pv4,    // packed [pos|vel], valid if PACKED
    const float* __restrict__ Wg,      // [64*3*3] (g, cin, cout)
    const int* __restrict__ nidx,      // [N][KMAX]
    const void* __restrict__ nmask,    // [N][KMAX], dtype detected per-wave
    float* __restrict__ out)           // [N][3]
{
    // W[c][0..7] as fp16 (one ds_read_b128/corner), W[c][8] as f32 (ds_read_b32).
    __shared__ _Float16 WsH[64 * 8];
    __shared__ float    Ws8[64];
    for (int t = threadIdx.x; t < 64 * 8; t += blockDim.x) {
        int g = t >> 3, r = t & 7;
        WsH[t] = (_Float16)Wg[g * 9 + r];
    }
    for (int t = threadIdx.x; t < 64; t += blockDim.x)
        Ws8[t] = Wg[t * 9 + 8];
    __syncthreads();

    int gid = blockIdx.x * blockDim.x + threadIdx.x;
    int p   = gid / LPP;
    int sub = gid & (LPP - 1);
    if (p >= N_PART) return;

    const int base = p * KMAX;

    // ---- hoist ALL nidx loads for this lane (sub + j*16 <= 79 always) ----
    int idxs[MAXTRIP];
    #pragma unroll
    for (int j = 0; j < MAXTRIP; ++j)
        idxs[j] = nidx[base + sub + j * LPP];

    // ---- per-wave mask-dtype detection (int32 vs byte-bool storage) ----
    // Any aligned u32 word >1 => byte-bools (consecutive Trues pack 0x01010101).
    bool byteMask;
    {
        const unsigned* mw = (const unsigned*)nmask;
        int lane = threadIdx.x & 63;
        bool big = false;
        #pragma unroll
        for (int i = 0; i < 8; ++i)
            big |= (mw[lane + 64 * i] > 1u);
        byteMask = (__ballot(big) != 0ULL);
    }

    // ---- issue first gather immediately ----
    float4 a, b;
    float  cpx, cpy, cpz;
    if (PACKED) {
        a = pv4[2 * idxs[0]];
        b = pv4[2 * idxs[0] + 1];
        float4 c = pv4[2 * p];
        cpx = c.x; cpy = c.y; cpz = c.z;
    } else {
        int i0 = idxs[0];
        a = make_float4(pos[i0*3], pos[i0*3+1], pos[i0*3+2], vel[i0*3]);
        b = make_float4(vel[i0*3+1], vel[i0*3+2], 0.f, 0.f);
        cpx = pos[p * 3 + 0]; cpy = pos[p * 3 + 1]; cpz = pos[p * 3 + 2];
    }

    int cnt;
    if (byteMask) cnt = prefix_count<unsigned char>((const unsigned char*)nmask, base, sub);
    else          cnt = prefix_count<int>((const int*)nmask, base, sub);

    int trips = (cnt > sub) ? ((cnt - sub + LPP - 1) >> 4) : 0;

    const float inv_r = 1.0f / 0.3f;
    const float eps   = 1e-12f;
    const float FOUR_OVER_PI = 1.27323954473516268615f;

    float acc0 = 0.0f, acc1 = 0.0f, acc2 = 0.0f;

    for (int j = 0; j < trips; ++j) {
        // ---- prefetch next trip's gather (index already in registers) ----
        int jn = (j + 1 < MAXTRIP) ? j + 1 : MAXTRIP - 1;
        float4 an, bn;
        if (PACKED) {
            an = pv4[2 * idxs[jn]];
            bn = pv4[2 * idxs[jn] + 1];
        } else {
            int ii = idxs[jn];
            an = make_float4(pos[ii*3], pos[ii*3+1], pos[ii*3+2], vel[ii*3]);
            bn = make_float4(vel[ii*3+1], vel[ii*3+2], 0.f, 0.f);
        }

        float rx = (a.x - cpx) * inv_r;
        float ry = (a.y - cpy) * inv_r;
        float rz = (a.z - cpz) * inv_r;
        float ux = a.w, uy = b.x, uz = b.y;

        float sq = rx * rx + ry * ry + rz * rz;

        // window_poly6 on normalized squared distance
        float t1  = 1.0f - sq;
        float imp = fminf(fmaxf(t1 * t1 * t1, 0.0f), 1.0f);

        // ---- ball -> cylinder (volume preserving), branch-lite ----
        float norm  = sqrtf(fmaxf(sq, eps));
        float sq_xy = rx * rx + ry * ry;
        bool  top   = (1.25f * rz * rz) > sq_xy;
        float s_top  = sqrtf(3.0f * norm * __builtin_amdgcn_rcpf(norm + fabsf(rz)));
        float s_side = norm * __builtin_amdgcn_rsqf(fmaxf(sq_xy, eps));
        float s  = top ? s_top : s_side;
        float x1 = rx * s;
        float y1 = ry * s;
        float z1 = top ? copysignf(norm, rz) : 1.5f * rz;
        if (sq < eps) { x1 = rx; y1 = ry; z1 = rz; }

        // ---- cylinder -> cube (equal-area disc -> square) ----
        float sq_xy1  = x1 * x1 + y1 * y1;
        float norm_xy = sqrtf(fmaxf(sq_xy1, eps));
        bool  xbig = fabsf(y1) <= fabsf(x1);
        float num  = xbig ? y1 : x1;
        float den  = xbig ? x1 : y1;
        float sden = (fabsf(den) > eps) ? den : 1.0f;
        float t    = num * __builtin_amdgcn_rcpf(sden);
        float at   = atan_poly(t);
        float sd   = copysignf(norm_xy, den);
        float u    = sd * FOUR_OVER_PI * at;
        float x2   = xbig ? sd : u;
        float y2   = xbig ? u  : sd;
        if (sq_xy1 < eps) { x2 = x1; y2 = y1; }

        // ---- trilinear grid coords, align_corners=True, clamped ----
        float tx = fminf(fmaxf((x2 + 1.0f) * 1.5f, 0.0f), 3.0f);
        float ty = fminf(fmaxf((y2 + 1.0f) * 1.5f, 0.0f), 3.0f);
        float tz = fminf(fmaxf((z1 + 1.0f) * 1.5f, 0.0f), 3.0f);
        float fx0 = floorf(tx), fy0 = floorf(ty), fz0 = floorf(tz);
        int xi0 = (int)fx0, yi0 = (int)fy0, zi0 = (int)fz0;
        int xi1 = min(xi0 + 1, KS - 1);
        int yi1 = min(yi0 + 1, KS - 1);
        int zi1 = min(zi0 + 1, KS - 1);
        float wx1 = tx - fx0, wx0 = 1.0f - wx1;
        float wy1 = ty - fy0, wy0 = 1.0f - wy1;
        float wz1 = tz - fz0, wz0 = 1.0f - wz1;

        int   zi[2] = { zi0, zi1 };  float wzv[2] = { wz0, wz1 };
        int   yi[2] = { yi0, yi1 };  float wyv[2] = { wy0, wy1 };
        int   xi[2] = { xi0, xi1 };  float wxv[2] = { wx0, wx1 };

        // ---- per-pair M = sum_c w_c * W_c, accumulated in packed fp16 ----
        h2 M01 = (h2)(_Float16)0.0f;
        h2 M23 = (h2)(_Float16)0.0f;
        h2 M45 = (h2)(_Float16)0.0f;
        h2 M67 = (h2)(_Float16)0.0f;
        float m8 = 0.0f;

        #pragma unroll
        for (int cz = 0; cz < 2; ++cz) {
            #pragma unroll
            for (int cy = 0; cy < 2; ++cy) {
                float wzy = wzv[cz] * wyv[cy];
                #pragma unroll
                for (int cx = 0; cx < 2; ++cx) {
                    int corner = (zi[cz] * KS + yi[cy]) * KS + xi[cx];
                    h8 wv = *(const h8*)&WsH[corner << 3];   // ds_read_b128
                    float wf = wzy * wxv[cx];
                    _Float16 wh = (_Float16)wf;
                    h2 ww = { wh, wh };
                    M01 += ww * __builtin_shufflevector(wv, wv, 0, 1);
                    M23 += ww * __builtin_shufflevector(wv, wv, 2, 3);
                    M45 += ww * __builtin_shufflevector(wv, wv, 4, 5);
                    M67 += ww * __builtin_shufflevector(wv, wv, 6, 7);
                    m8  += wf * Ws8[corner];                 // ds_read_b32
                }
            }
        }

        // ---- fold: acc += imp * (M^T u);  M layout = [cin*3+cout], m8 = M[2][2]
        float m0 = (float)M01[0], m1 = (float)M01[1];
        float m2 = (float)M23[0], m3 = (float)M23[1];
        float m4 = (float)M45[0], m5 = (float)M45[1];
        float m6 = (float)M67[0], m7 = (float)M67[1];
        float s0 = ux * m0 + uy * m3 + uz * m6;
        float s1 = ux * m1 + uy * m4 + uz * m7;
        float s2 = ux * m2 + uy * m5 + uz * m8;
        acc0 += imp * s0;
        acc1 += imp * s1;
        acc2 += imp * s2;

        a = an; b = bn;
    }

    // reduce across the 16 lanes of this particle
    acc0 += __shfl_xor(acc0, 1); acc0 += __shfl_xor(acc0, 2);
    acc0 += __shfl_xor(acc0, 4); acc0 += __shfl_xor(acc0, 8);
    acc1 += __shfl_xor(acc1, 1); acc1 += __shfl_xor(acc1, 2);
    acc1 += __shfl_xor(acc1, 4); acc1 += __shfl_xor(acc1, 8);
    acc2 += __shfl_xor(acc2, 1); acc2 += __shfl_xor(acc2, 2);
    acc2 += __shfl_xor(acc2, 4); acc2 += __shfl_xor(acc2, 8);

    if (sub == 0) {
        out[p * 3 + 0] = acc0;
        out[p * 3 + 1] = acc1;
        out[p * 3 + 2] = acc2;
    }
}

extern "C" void kernel_launch(void* const* d_in, const int* in_sizes, int n_in,
                              void* d_out, int out_size, void* d_ws, size_t ws_size,
                              hipStream_t stream) {
    const float* pos   = (const float*)d_in[0];
    const float* vel   = (const float*)d_in[1];
    const float* Wg    = (const float*)d_in[2];
    const int*   nidx  = (const int*)d_in[3];
    const void*  nmask = d_in[4];
    float*       out   = (float*)d_out;

    size_t pv_off = 256;
    size_t need   = pv_off + (size_t)N_PART * 8 * sizeof(float);
    bool   packed = ws_size >= need;
    float4* pv4   = (float4*)((char*)d_ws + pv_off);

    if (packed) {
        pack_pv_kernel<<<(N_PART + 255) / 256, 256, 0, stream>>>(pos, vel, pv4);
    }

    int threads = 256;
    long long total = (long long)N_PART * LPP;
    int grid = (int)((total + threads - 1) / threads);
    if (packed) {
        cconv_kernel<true><<<grid, threads, 0, stream>>>(pos, vel, pv4, Wg, nidx, nmask, out);
    } else {
        cconv_kernel<false><<<grid, threads, 0, stream>>>(pos, vel, (const float4*)nullptr, Wg, nidx, nmask, out);
    }
}

// Round 8
// 33.054 us; speedup vs baseline: 1.9344x; 1.0217x over previous
//
#include <hip/hip_runtime.h>
#include <math.h>

#define N_PART 50000
#define KMAX 80
#define KS 4
#define LPP 16   // lanes per particle; dual-pair stride = 32

typedef __attribute__((ext_vector_type(8))) _Float16 h8;
typedef __attribute__((ext_vector_type(2))) _Float16 h2;

// minimax odd polynomial for atan(t), t in [-1,1]; max abs err ~1e-5
__device__ __forceinline__ float atan_poly(float t) {
    float t2 = t * t;
    float p = -0.01172120f;
    p = p * t2 + 0.05265332f;
    p = p * t2 - 0.11643287f;
    p = p * t2 + 0.19354346f;
    p = p * t2 - 0.33262347f;
    p = p * t2 + 0.99997726f;
    return t * p;
}

// Count the true-prefix length of row p using this particle's 16 lanes.
template <typename MT>
__device__ __forceinline__ int prefix_count(const MT* __restrict__ nmask, int base, int sub) {
    int lc = 0; bool more = true;
    #pragma unroll
    for (int i = 0; i < 5; ++i) {
        bool t = nmask[base + sub * 5 + i] != 0;
        lc += (more && t) ? 1 : 0;
        more = more && t;
    }
    bool full = (lc == 5);
    unsigned long long nb = __ballot(!full);
    int wl  = threadIdx.x & 63;
    int grp = wl >> 4;
    unsigned int gb = (unsigned int)((nb >> (16 * grp)) & 0xFFFFull);
    if (gb == 0) return KMAX;
    int fi  = __ffs(gb) - 1;
    int flc = __shfl(lc, (grp << 4) + fi, 64);
    return fi * 5 + flc;
}

struct PV { float px, py, pz, ux, uy, uz; };

__device__ __forceinline__ void load_pv(const float* __restrict__ pos,
                                        const float* __restrict__ vel,
                                        int i, PV& v) {
    v.px = pos[3*i];  v.py = pos[3*i+1];  v.pz = pos[3*i+2];
    v.ux = vel[3*i];  v.uy = vel[3*i+1];  v.uz = vel[3*i+2];
}

// One pair's full contribution (transform + corner fold), added into acc.
// vmask in {0,1} zeroes masked slots via imp.
__device__ __forceinline__ void pair_contrib(
    const PV& n, float cpx, float cpy, float cpz, float vmask,
    const _Float16* __restrict__ WsH, const float* __restrict__ Ws8,
    float& acc0, float& acc1, float& acc2)
{
    const float inv_r = 1.0f / 0.3f;
    const float eps   = 1e-12f;
    const float FOUR_OVER_PI = 1.27323954473516268615f;

    float rx = (n.px - cpx) * inv_r;
    float ry = (n.py - cpy) * inv_r;
    float rz = (n.pz - cpz) * inv_r;

    float sq = rx * rx + ry * ry + rz * rz;

    // window_poly6 on normalized squared distance (vmask folded in)
    float t1  = 1.0f - sq;
    float imp = fminf(fmaxf(t1 * t1 * t1, 0.0f), 1.0f) * vmask;

    // ---- ball -> cylinder (volume preserving), branch-lite ----
    float norm  = sqrtf(fmaxf(sq, eps));
    float sq_xy = rx * rx + ry * ry;
    bool  top   = (1.25f * rz * rz) > sq_xy;
    float s_top  = sqrtf(3.0f * norm * __builtin_amdgcn_rcpf(norm + fabsf(rz)));
    float s_side = norm * __builtin_amdgcn_rsqf(fmaxf(sq_xy, eps));
    float s  = top ? s_top : s_side;
    float x1 = rx * s;
    float y1 = ry * s;
    float z1 = top ? copysignf(norm, rz) : 1.5f * rz;
    if (sq < eps) { x1 = rx; y1 = ry; z1 = rz; }

    // ---- cylinder -> cube (equal-area disc -> square) ----
    float sq1 = x1 * x1 + y1 * y1;
    float nxy = sqrtf(fmaxf(sq1, eps));
    bool  xb  = fabsf(y1) <= fabsf(x1);
    float num = xb ? y1 : x1;
    float den = xb ? x1 : y1;
    float sden = (fabsf(den) > eps) ? den : 1.0f;
    float t    = num * __builtin_amdgcn_rcpf(sden);
    float at   = atan_poly(t);
    float sd   = copysignf(nxy, den);
    float u    = sd * FOUR_OVER_PI * at;
    float x2   = xb ? sd : u;
    float y2   = xb ? u  : sd;
    if (sq1 < eps) { x2 = x1; y2 = y1; }

    // ---- trilinear grid coords, align_corners=True, clamped ----
    float tx = fminf(fmaxf((x2 + 1.0f) * 1.5f, 0.0f), 3.0f);
    float ty = fminf(fmaxf((y2 + 1.0f) * 1.5f, 0.0f), 3.0f);
    float tz = fminf(fmaxf((z1 + 1.0f) * 1.5f, 0.0f), 3.0f);
    float fx0 = floorf(tx), fy0 = floorf(ty), fz0 = floorf(tz);
    int xi0 = (int)fx0, yi0 = (int)fy0, zi0 = (int)fz0;
    int xi1 = min(xi0 + 1, KS - 1);
    int yi1 = min(yi0 + 1, KS - 1);
    int zi1 = min(zi0 + 1, KS - 1);
    float wx1 = tx - fx0, wx0 = 1.0f - wx1;
    float wy1 = ty - fy0, wy0 = 1.0f - wy1;
    float wz1 = tz - fz0, wz0 = 1.0f - wz1;

    int   zia[2] = { zi0, zi1 };  float wza[2] = { wz0, wz1 };
    int   yia[2] = { yi0, yi1 };  float wya[2] = { wy0, wy1 };
    int   xia[2] = { xi0, xi1 };  float wxa[2] = { wx0, wx1 };

    // ---- per-pair M = sum_c w_c * W_c, accumulated in packed fp16 ----
    h2 M01 = (h2)(_Float16)0.0f;
    h2 M23 = (h2)(_Float16)0.0f;
    h2 M45 = (h2)(_Float16)0.0f;
    h2 M67 = (h2)(_Float16)0.0f;
    float m8 = 0.0f;

    #pragma unroll
    for (int cz = 0; cz < 2; ++cz) {
        #pragma unroll
        for (int cy = 0; cy < 2; ++cy) {
            float wzy = wza[cz] * wya[cy];
            #pragma unroll
            for (int cx = 0; cx < 2; ++cx) {
                int corner = (zia[cz] * KS + yia[cy]) * KS + xia[cx];
                h8 wv = *(const h8*)&WsH[corner << 3];   // ds_read_b128
                float wf = wzy * wxa[cx];
                _Float16 wh = (_Float16)wf;
                h2 ww = { wh, wh };
                M01 += ww * __builtin_shufflevector(wv, wv, 0, 1);
                M23 += ww * __builtin_shufflevector(wv, wv, 2, 3);
                M45 += ww * __builtin_shufflevector(wv, wv, 4, 5);
                M67 += ww * __builtin_shufflevector(wv, wv, 6, 7);
                m8  += wf * Ws8[corner];                 // ds_read_b32
            }
        }
    }

    // ---- fold: acc += imp * (M^T u);  M layout = [cin*3+cout], m8 = M[2][2]
    float m0 = (float)M01[0], m1 = (float)M01[1];
    float m2 = (float)M23[0], m3 = (float)M23[1];
    float m4 = (float)M45[0], m5 = (float)M45[1];
    float m6 = (float)M67[0], m7 = (float)M67[1];
    float s0 = n.ux * m0 + n.uy * m3 + n.uz * m6;
    float s1 = n.ux * m1 + n.uy * m4 + n.uz * m7;
    float s2 = n.ux * m2 + n.uy * m5 + n.uz * m8;
    acc0 += imp * s0;
    acc1 += imp * s1;
    acc2 += imp * s2;
}

__global__ __launch_bounds__(256) void cconv_kernel(
    const float* __restrict__ pos,
    const float* __restrict__ vel,
    const float* __restrict__ Wg,      // [64*3*3] (g, cin, cout)
    const int* __restrict__ nidx,      // [N][KMAX]
    const void* __restrict__ nmask,    // [N][KMAX], dtype detected per-wave
    float* __restrict__ out)           // [N][3]
{
    // W[c][0..7] as fp16 (one ds_read_b128/corner), W[c][8] as f32 (ds_read_b32).
    __shared__ _Float16 WsH[64 * 8];
    __shared__ float    Ws8[64];
    for (int t = threadIdx.x; t < 64 * 8; t += blockDim.x) {
        int g = t >> 3, r = t & 7;
        WsH[t] = (_Float16)Wg[g * 9 + r];
    }
    for (int t = threadIdx.x; t < 64; t += blockDim.x)
        Ws8[t] = Wg[t * 9 + 8];
    __syncthreads();

    int gid = blockIdx.x * blockDim.x + threadIdx.x;
    int p   = gid >> 4;        // 16 lanes per particle; 800000/256 = exact grid
    int sub = gid & 15;
    if (p >= N_PART) return;

    const int base = p * KMAX;

    // ---- hoist ALL nidx loads for this lane (sub + m*16 <= 79 always) ----
    int idxs[5];
    #pragma unroll
    for (int m = 0; m < 5; ++m)
        idxs[m] = nidx[base + sub + (m << 4)];

    // ---- per-wave mask-dtype detection (int32 vs byte-bool storage) ----
    bool byteMask;
    {
        const unsigned* mw = (const unsigned*)nmask;
        int lane = threadIdx.x & 63;
        bool big = false;
        #pragma unroll
        for (int i = 0; i < 8; ++i)
            big |= (mw[lane + 64 * i] > 1u);
        byteMask = (__ballot(big) != 0ULL);
    }

    float cpx = pos[3 * p], cpy = pos[3 * p + 1], cpz = pos[3 * p + 2];

    int cnt;
    if (byteMask) cnt = prefix_count<unsigned char>((const unsigned char*)nmask, base, sub);
    else          cnt = prefix_count<int>((const int*)nmask, base, sub);

    // Lane handles pairs k0 = sub + 32j (unmasked: loop bound guarantees k0 < cnt)
    // and k1 = k0 + 16 (masked by k1 < cnt). Decomposition k = sub + 16m covers
    // every k < cnt exactly once across (lane, j, slot).
    int rem   = cnt - sub;
    int trips = (rem > 0) ? ((rem + 31) >> 5) : 0;

    PV A0, A1, A0n, A1n;
    load_pv(pos, vel, idxs[0], A0);
    load_pv(pos, vel, idxs[1], A1);

    float acc0 = 0.0f, acc1 = 0.0f, acc2 = 0.0f;

    for (int j = 0; j < trips; ++j) {
        // prefetch both next-iteration pairs (indices already in registers)
        int mn0 = min(2 * j + 2, 4);
        int mn1 = min(2 * j + 3, 4);
        load_pv(pos, vel, idxs[mn0], A0n);
        load_pv(pos, vel, idxs[mn1], A1n);

        int   k1 = sub + ((2 * j + 1) << 4);
        float v1 = (k1 < cnt) ? 1.0f : 0.0f;

        // two independent chains -> compiler interleaves for ILP
        pair_contrib(A0, cpx, cpy, cpz, 1.0f, WsH, Ws8, acc0, acc1, acc2);
        pair_contrib(A1, cpx, cpy, cpz, v1,   WsH, Ws8, acc0, acc1, acc2);

        A0 = A0n; A1 = A1n;
    }

    // reduce across the 16 lanes of this particle
    acc0 += __shfl_xor(acc0, 1); acc0 += __shfl_xor(acc0, 2);
    acc0 += __shfl_xor(acc0, 4); acc0 += __shfl_xor(acc0, 8);
    acc1 += __shfl_xor(acc1, 1); acc1 += __shfl_xor(acc1, 2);
    acc1 += __shfl_xor(acc1, 4); acc1 += __shfl_xor(acc1, 8);
    acc2 += __shfl_xor(acc2, 1); acc2 += __shfl_xor(acc2, 2);
    acc2 += __shfl_xor(acc2, 4); acc2 += __shfl_xor(acc2, 8);

    if (sub == 0) {
        out[p * 3 + 0] = acc0;
        out[p * 3 + 1] = acc1;
        out[p * 3 + 2] = acc2;
    }
}

extern "C" void kernel_launch(void* const* d_in, const int* in_sizes, int n_in,
                              void* d_out, int out_size, void* d_ws, size_t ws_size,
                              hipStream_t stream) {
    const float* pos   = (const float*)d_in[0];
    const float* vel   = (const float*)d_in[1];
    const float* Wg    = (const float*)d_in[2];
    const int*   nidx  = (const int*)d_in[3];
    const void*  nmask = d_in[4];
    float*       out   = (float*)d_out;

    int threads = 256;
    long long total = (long long)N_PART * LPP;
    int grid = (int)((total + threads - 1) / threads);
    cconv_kernel<<<grid, threads, 0, stream>>>(pos, vel, Wg, nidx, nmask, out);
}